// Round 2
// baseline (100.326 us; speedup 1.0000x reference)
//
#include <hip/hip_runtime.h>

#define Bb 4
#define AT 384
#define NBR 24
#define FEAT 128
#define ROWQ (FEAT / 4)          // 32 float4 per feature row
#define PANELQ (NBR * ROWQ)      // 768 float4 per (b,a) edge panel

// One block per (b, a). Builds the full 24x24 match mask in LDS once, then
// streams the masked copy out[b,a,j,i,:] = mask[j][i] ? edge[b,a,i,:] : 0
// as 24 * 768 coalesced float4 stores (288 KB per block).
__global__ __launch_bounds__(256) void GetEdgeJK_kernel(
    const float4* __restrict__ edge,  // (B, AT, NBR, FEAT) viewed as float4
    const int*    __restrict__ nbr,   // (B, AT, NBR)
    const float*  __restrict__ cell,  // (B, AT, NBR, 3)
    float4*       __restrict__ out)   // (B, AT, NBR_j, NBR_i, FEAT) as float4
{
    const int ba = blockIdx.x;        // b*AT + a
    const int b  = ba / AT;
    const int t  = threadIdx.x;

    __shared__ int   s_nbr[NBR];               // nbr[b,a,:]
    __shared__ float s_cell[NBR][3];           // cell[b,a,:,:]
    __shared__ int   s_nbrj[NBR][NBR];         // nbr[b, nbr[b,a,j], k]
    __shared__ float s_cellj[NBR][NBR][3];     // cell[b, nbr[b,a,j], k, :]
    __shared__ int   s_mask[NBR * NBR];        // [j*NBR + i]

    // stage this atom's neighbor row
    if (t < NBR) {
        s_nbr[t]     = nbr[ba * NBR + t];
        s_cell[t][0] = cell[(ba * NBR + t) * 3 + 0];
        s_cell[t][1] = cell[(ba * NBR + t) * 3 + 1];
        s_cell[t][2] = cell[(ba * NBR + t) * 3 + 2];
    }
    __syncthreads();

    // stage neighbors-of-neighbors: for each (j,k), nbr/cell of atom nbr[b,a,j]
    for (int q = t; q < NBR * NBR; q += 256) {
        const int j = q / NBR;
        const int k = q % NBR;
        const int base = (b * AT + s_nbr[j]) * NBR + k;
        s_nbrj[j][k]     = nbr[base];
        s_cellj[j][k][0] = cell[base * 3 + 0];
        s_cellj[j][k][1] = cell[base * 3 + 1];
        s_cellj[j][k][2] = cell[base * 3 + 2];
    }
    __syncthreads();

    // mask[j][i] = (i != j) && exists k: idx match && cell match
    for (int p = t; p < NBR * NBR; p += 256) {
        const int j = p / NBR;
        const int i = p % NBR;
        int m = 0;
        if (i != j) {
            const int   myidx = s_nbr[i];
            const float c0 = s_cell[i][0];
            const float c1 = s_cell[i][1];
            const float c2 = s_cell[i][2];
            #pragma unroll
            for (int k = 0; k < NBR; ++k) {
                if (s_nbrj[j][k] == myidx &&
                    s_cellj[j][k][0] == c0 &&
                    s_cellj[j][k][1] == c1 &&
                    s_cellj[j][k][2] == c2) { m = 1; }
            }
        }
        s_mask[p] = m;
    }
    __syncthreads();

    // stream the masked copy: 24 j-rows x 768 float4 each
    const float4* __restrict__ erow = edge + (size_t)ba * PANELQ;
    float4*       __restrict__ orow = out  + (size_t)ba * NBR * PANELQ;
    const float4 zero = make_float4(0.f, 0.f, 0.f, 0.f);

    for (int j = 0; j < NBR; ++j) {
        const int* __restrict__ mrow = &s_mask[j * NBR];
        #pragma unroll
        for (int it = 0; it < 3; ++it) {
            const int q = it * 256 + t;   // [0, 768)
            const int i = q >> 5;         // neighbor row (32 float4 per row)
            float4 v = zero;
            if (mrow[i]) v = erow[q];     // uniform per 32-thread subgroup
            orow[j * PANELQ + q] = v;
        }
    }
}

extern "C" void kernel_launch(void* const* d_in, const int* in_sizes, int n_in,
                              void* d_out, int out_size, void* d_ws, size_t ws_size,
                              hipStream_t stream) {
    const float4* edge = (const float4*)d_in[0];
    const int*    nbr  = (const int*)d_in[1];
    const float*  cell = (const float*)d_in[2];
    float4*       out  = (float4*)d_out;

    const int nblocks = Bb * AT;   // 1536 blocks, one per (b,a)
    GetEdgeJK_kernel<<<nblocks, 256, 0, stream>>>(edge, nbr, cell, out);
}

// Round 4
// 95.046 us; speedup vs baseline: 1.0556x; 1.0556x over previous
//
#include <hip/hip_runtime.h>

#define Bb 4
#define AT 384
#define NBR 24
#define FEAT 128
#define ROWQ (FEAT / 4)          // 32 float4 per feature row
#define PANELQ (NBR * ROWQ)      // 768 float4 per (b,a) edge panel

typedef float vfloat4 __attribute__((ext_vector_type(4)));

// ---------------- Kernel A: mask precompute ----------------
// One block per (b,a). Builds the 24x24 match mask and packs it into 24
// uint32 words (bit i of word j = mask[j][i]) written to ws[ba*24 + j].
__global__ __launch_bounds__(256) void mask_kernel(
    const int*   __restrict__ nbr,    // (B, AT, NBR)
    const float* __restrict__ cell,   // (B, AT, NBR, 3)
    unsigned int* __restrict__ ws)    // (B*AT*NBR) mask words
{
    const int ba = blockIdx.x;
    const int b  = ba / AT;
    const int t  = threadIdx.x;

    __shared__ int   s_nbr[NBR];
    __shared__ float s_cell[NBR][3];
    __shared__ int   s_nbrj[NBR][NBR];
    __shared__ float s_cellj[NBR][NBR][3];
    __shared__ int   s_mask[NBR * NBR];

    if (t < NBR) {
        s_nbr[t]     = nbr[ba * NBR + t];
        s_cell[t][0] = cell[(ba * NBR + t) * 3 + 0];
        s_cell[t][1] = cell[(ba * NBR + t) * 3 + 1];
        s_cell[t][2] = cell[(ba * NBR + t) * 3 + 2];
    }
    __syncthreads();

    for (int q = t; q < NBR * NBR; q += 256) {
        const int j = q / NBR;
        const int k = q % NBR;
        const int base = (b * AT + s_nbr[j]) * NBR + k;
        s_nbrj[j][k]     = nbr[base];
        s_cellj[j][k][0] = cell[base * 3 + 0];
        s_cellj[j][k][1] = cell[base * 3 + 1];
        s_cellj[j][k][2] = cell[base * 3 + 2];
    }
    __syncthreads();

    for (int p = t; p < NBR * NBR; p += 256) {
        const int j = p / NBR;
        const int i = p % NBR;
        int m = 0;
        if (i != j) {
            const int   myidx = s_nbr[i];
            const float c0 = s_cell[i][0];
            const float c1 = s_cell[i][1];
            const float c2 = s_cell[i][2];
            #pragma unroll
            for (int k = 0; k < NBR; ++k) {
                if (s_nbrj[j][k] == myidx &&
                    s_cellj[j][k][0] == c0 &&
                    s_cellj[j][k][1] == c1 &&
                    s_cellj[j][k][2] == c2) { m = 1; }
            }
        }
        s_mask[p] = m;
    }
    __syncthreads();

    if (t < NBR) {
        const int j = t;
        unsigned int w = 0;
        #pragma unroll
        for (int i = 0; i < NBR; ++i)
            w |= (unsigned int)s_mask[j * NBR + i] << i;
        ws[ba * NBR + j] = w;
    }
}

// ---------------- Kernel B: masked streaming fill ----------------
// One block per (b,a,j). Uniform scalar mask word, then 3 coalesced 16B
// nontemporal stores per thread (12 KB/block). Structurally fillBuffer+branch.
__global__ __launch_bounds__(256) void store_kernel(
    const vfloat4* __restrict__ edge,       // (B, AT, NBR, FEAT) as 16B vecs
    const unsigned int* __restrict__ ws,    // mask words
    vfloat4*       __restrict__ out)        // (B, AT, NBR_j, NBR_i, FEAT)
{
    const int blk = blockIdx.x;             // (b*AT + a)*NBR + j
    const int ba  = blk / NBR;
    const int t   = threadIdx.x;

    const unsigned int m = ws[blk];         // wave-uniform scalar load

    const vfloat4* __restrict__ erow = edge + (size_t)ba * PANELQ;
    vfloat4*       __restrict__ orow = out  + (size_t)blk * PANELQ;
    const vfloat4 zero = (vfloat4)(0.f);

    #pragma unroll
    for (int it = 0; it < 3; ++it) {
        const int q = it * 256 + t;         // [0, 768)
        const int i = q >> 5;               // neighbor row
        vfloat4 v = zero;
        if ((m >> i) & 1u) v = erow[q];     // uniform per 32-thread subgroup
        __builtin_nontemporal_store(v, &orow[q]);
    }
}

// ---------------- Fallback: R1 monolithic kernel (if ws too small) --------
__global__ __launch_bounds__(256) void mono_kernel(
    const float* __restrict__ edge,
    const int*   __restrict__ nbr,
    const float* __restrict__ cell,
    float*       __restrict__ out)
{
    const int blk = blockIdx.x;
    const int j   = blk % NBR;
    const int ba  = blk / NBR;
    const int b   = ba / AT;

    __shared__ int   s_nbrj[NBR];
    __shared__ float s_cellj[NBR][3];
    __shared__ int   s_mask[NBR];

    const int t = threadIdx.x;
    const int jatom = nbr[ba * NBR + j];

    if (t < NBR) {
        const int base = (b * AT + jatom) * NBR + t;
        s_nbrj[t]     = nbr[base];
        s_cellj[t][0] = cell[base * 3 + 0];
        s_cellj[t][1] = cell[base * 3 + 1];
        s_cellj[t][2] = cell[base * 3 + 2];
    }
    __syncthreads();

    if (t < NBR) {
        const int i = t;
        int m = 0;
        if (i != j) {
            const int   myidx = nbr[ba * NBR + i];
            const float c0 = cell[(ba * NBR + i) * 3 + 0];
            const float c1 = cell[(ba * NBR + i) * 3 + 1];
            const float c2 = cell[(ba * NBR + i) * 3 + 2];
            #pragma unroll
            for (int k = 0; k < NBR; ++k) {
                if (s_nbrj[k] == myidx &&
                    s_cellj[k][0] == c0 &&
                    s_cellj[k][1] == c1 &&
                    s_cellj[k][2] == c2) { m = 1; }
            }
        }
        s_mask[i] = m;
    }
    __syncthreads();

    const float4* __restrict__ erow = (const float4*)(edge + (size_t)ba * NBR * FEAT);
    float4*       __restrict__ orow = (float4*)(out + (size_t)blk * NBR * FEAT);
    const float4 zero = make_float4(0.f, 0.f, 0.f, 0.f);
    #pragma unroll
    for (int it = 0; it < 3; ++it) {
        const int q = t + it * 256;
        const int i = q >> 5;
        float4 v = zero;
        if (s_mask[i]) v = erow[q];
        orow[q] = v;
    }
}

extern "C" void kernel_launch(void* const* d_in, const int* in_sizes, int n_in,
                              void* d_out, int out_size, void* d_ws, size_t ws_size,
                              hipStream_t stream) {
    const float* edge = (const float*)d_in[0];
    const int*   nbr  = (const int*)d_in[1];
    const float* cell = (const float*)d_in[2];
    float*       out  = (float*)d_out;

    const size_t need = (size_t)Bb * AT * NBR * sizeof(unsigned int);  // 147 KB
    if (ws_size >= need) {
        unsigned int* ws = (unsigned int*)d_ws;
        mask_kernel<<<Bb * AT, 256, 0, stream>>>(nbr, cell, ws);
        store_kernel<<<Bb * AT * NBR, 256, 0, stream>>>((const vfloat4*)edge, ws,
                                                        (vfloat4*)out);
    } else {
        mono_kernel<<<Bb * AT * NBR, 256, 0, stream>>>(edge, nbr, cell, out);
    }
}